// Round 12
// baseline (145.747 us; speedup 1.0000x reference)
//
#include <hip/hip_runtime.h>
#include <hip/hip_bf16.h>

typedef __attribute__((ext_vector_type(8))) short short8;
typedef __attribute__((ext_vector_type(4))) float f32x4;

#define DEVI __device__ __forceinline__

constexpr int SEQ = 4096;
constexpr int HD = 1024;      // d_model
constexpr int NS = 512;       // ssm size
constexpr int NB = 4;         // batch
constexpr int MROWS = NB * SEQ;        // 16384
constexpr int NCH = 128;               // chunks along L (was 64; more TLP)
constexpr int CLEN = SEQ / NCH;        // 32

// ---- workspace byte offsets ----
constexpr size_t MB = 1024 * 1024;
constexpr size_t OFF_UBF = 0;                 // u bf16 (M x 1024) 32 MiB
constexpr size_t OFF_W1  = 32 * MB;           // W1t (1024 x 1024 bf16) 2 MiB
constexpr size_t OFF_W2  = 34 * MB;           // W2t 2 MiB
constexpr size_t OFF_P   = 36 * MB;           // per-n params (64 KiB reserved)
constexpr size_t OFF_BU  = 36 * MB + 65536;   // Bu bf16 (M x 1024) 32 MiB
constexpr size_t OFF_T   = OFF_BU + 32 * MB;  // chunk totals (f32) 2 MiB
constexpr size_t OFF_CRY = OFF_T + 2 * MB;    // carries (f32) 2 MiB
constexpr size_t OFF_SBF = OFF_CRY + 2 * MB;  // state bf16 32 MiB
constexpr size_t OFF_STF = OFF_SBF + 32 * MB; // state-real f32 fallback 32 MiB

DEVI float bf2f(unsigned short u) {
    union { unsigned u32; float f; } x; x.u32 = (unsigned)u << 16; return x.f;
}

// ============ prep: per-n lambda_bar and f = (lb-1)/Lambda ============
__global__ void prep_params(const float* __restrict__ Lre, const float* __restrict__ Lim,
                            const float* __restrict__ step, float* __restrict__ P) {
    int n = blockIdx.x * 64 + threadIdx.x;
    if (n >= NS) return;
    float dt  = expf(step[n]);
    float lre = fminf(Lre[n], -1e-4f);
    float lim = Lim[n];
    float wre = lre * dt, wim = lim * dt;
    float s, c;
    sincosf(wim, &s, &c);
    float e = expf(wre);
    float lbre = e * c, lbim = e * s;
    float em1 = expm1f(wre);
    float sh  = sinf(0.5f * wim);
    float nr  = em1 * c - 2.0f * sh * sh;   // e^wre*cos(wim) - 1
    float ni  = e * s;
    float d2  = lre * lre + lim * lim;
    float inv = 1.0f / d2;
    float fre = (nr * lre + ni * lim) * inv;
    float fim = (ni * lre - nr * lim) * inv;
    float* p = P + n * 6;
    p[0] = wre; p[1] = wim; p[2] = lbre; p[3] = lbim; p[4] = fre; p[5] = fim;
}

// ====== merged weight build: blocks [0,2048) -> W1t, [2048,4096) -> W2t ======
__global__ void build_weights(const float* __restrict__ Bin, const float* __restrict__ Cin,
                              const float* __restrict__ P,
                              __hip_bfloat16* __restrict__ W1t,
                              __hip_bfloat16* __restrict__ W2t) {
    int bid = blockIdx.x;
    if (bid < 2048) {
        int idx = bid * 256 + threadIdx.x;          // n*HD + k
        int n = idx >> 10, k = idx & 1023;
        float fre = P[n * 6 + 4], fim = P[n * 6 + 5];
        float bre = Bin[(size_t)idx * 2 + 0], bim = Bin[(size_t)idx * 2 + 1];
        W1t[(size_t)(2 * n) * HD + k]     = __float2bfloat16(fre * bre - fim * bim);
        W1t[(size_t)(2 * n + 1) * HD + k] = __float2bfloat16(fre * bim + fim * bre);
    } else {
        int idx = (bid - 2048) * 256 + threadIdx.x; // h*NS + n
        int h = idx >> 9, n = idx & 511;
        float cre = Cin[(size_t)idx * 2 + 0], cim = Cin[(size_t)idx * 2 + 1];
        W2t[(size_t)h * HD + 2 * n]     = __float2bfloat16(cre);
        W2t[(size_t)h * HD + 2 * n + 1] = __float2bfloat16(-cim);
    }
}

// ============ f32 -> bf16 cast, 8/thread ============
__global__ void cast_to_bf16(const float* __restrict__ x, __hip_bfloat16* __restrict__ y, int n8) {
    int i = blockIdx.x * 256 + threadIdx.x;
    if (i >= n8) return;
    const float4* xv = (const float4*)x;
    float4 a = xv[2 * (size_t)i], b = xv[2 * (size_t)i + 1];
    union { __hip_bfloat16 h[8]; short8 v; } u8;
    u8.h[0] = __float2bfloat16(a.x); u8.h[1] = __float2bfloat16(a.y);
    u8.h[2] = __float2bfloat16(a.z); u8.h[3] = __float2bfloat16(a.w);
    u8.h[4] = __float2bfloat16(b.x); u8.h[5] = __float2bfloat16(b.y);
    u8.h[6] = __float2bfloat16(b.z); u8.h[7] = __float2bfloat16(b.w);
    *((short8*)(y + (size_t)i * 8)) = u8.v;
}

// ========== GEMM 256x256, BK=64, 8 waves, dbuf, counted vmcnt + XOR swizzle ======
// Round-11 base (passed, 138.1us) + T5: setprio(1) around each MFMA cluster.
DEVI void gload16(const __hip_bfloat16* g, __hip_bfloat16* l) {
    __builtin_amdgcn_global_load_lds(
        (const __attribute__((address_space(1))) unsigned int*)g,
        (__attribute__((address_space(3))) unsigned int*)l,
        16, 0, 0);
}

#define BARRIER_RAW() { asm volatile("" ::: "memory"); __builtin_amdgcn_s_barrier(); asm volatile("" ::: "memory"); }

template <int EPI>
__global__ __launch_bounds__(512, 2) void gemm_bf16_256(
    const __hip_bfloat16* __restrict__ A,   // M x 1024 row-major
    const __hip_bfloat16* __restrict__ Bt,  // 1024 x 1024 row-major (N x K)
    void* __restrict__ CoutV,               // M x 1024 (bf16 if EPI==0, f32 if EPI==1)
    const float* __restrict__ Dvec,         // [1024] (EPI==1)
    const __hip_bfloat16* __restrict__ Ubf) // M x 1024 bf16 (EPI==1)
{
    // 2 dbuf x (A,B) x 256 rows x 64 cols bf16 = 128 KiB
    __shared__ __hip_bfloat16 As[2][256 * 64];
    __shared__ __hip_bfloat16 Bs[2][256 * 64];
    const int tid  = threadIdx.x;
    const int lane = tid & 63;
    const int wid  = tid >> 6;                  // 0..7
    const size_t bm = (size_t)blockIdx.x * 256;
    const size_t bn = (size_t)blockIdx.y * 256;
    const int wr = (wid >> 2) * 128;            // wave row origin: 0 / 128
    const int wc = (wid & 3) * 64;              // wave col origin: 0..192
    const int fr = lane & 15;
    const int fq = lane >> 4;

    f32x4 acc[8][4];
#pragma unroll
    for (int i = 0; i < 8; ++i)
#pragma unroll
        for (int j = 0; j < 4; ++j) acc[i][j] = (f32x4){0.f, 0.f, 0.f, 0.f};

    const int srow = tid >> 3;          // 0..63 per round (row within 64-row group)
    const int schk = tid & 7;           // logical 16B chunk 0..7

    // Pre-swizzled global column: LDS chunk (tid&7) receives global chunk
    // ((tid&7) ^ (row&7)). Involution: read of logical chunk c at row r uses
    // physical chunk c^(r&7)  ->  global col (c^(r&7))^(r&7) = c.
#define STAGE(buf, kt)                                                          \
    {                                                                           \
        _Pragma("unroll")                                                       \
        for (int q = 0; q < 4; ++q) {                                           \
            int row = q * 64 + srow;                                            \
            int gcol = (schk ^ (row & 7)) * 8;                                  \
            gload16(A  + (bm + row) * 1024 + (kt) + gcol, &As[buf][(row * 8 + schk) * 8]); \
            gload16(Bt + (bn + row) * 1024 + (kt) + gcol, &Bs[buf][(row * 8 + schk) * 8]); \
        }                                                                       \
    }

    // prologue: tile 0 staged and fully drained
    STAGE(0, 0);
    __syncthreads();

    int cur = 0;
    for (int t = 0; t < 16; ++t) {
        if (t < 15) {
            STAGE(cur ^ 1, (t + 1) * 64);   // 8 loads for tile t+1 — stay in flight
            asm volatile("s_waitcnt vmcnt(8)" ::: "memory");   // tile t's 8 retired
        } else {
            asm volatile("s_waitcnt vmcnt(0)" ::: "memory");   // final tile: drain
        }
        __builtin_amdgcn_sched_barrier(0);
        BARRIER_RAW();          // cross-wave: everyone's tile-t loads retired

#pragma unroll
        for (int kh = 0; kh < 2; ++kh) {
            short8 af[8], bf_[4];
#pragma unroll
            for (int m = 0; m < 8; ++m) {
                int r = wr + m * 16 + fr;
                int pc = (kh * 4 + fq) ^ (r & 7);           // physical 16B chunk
                af[m] = *(const short8*)(&As[cur][(r * 8 + pc) * 8]);
            }
#pragma unroll
            for (int n = 0; n < 4; ++n) {
                int r = wc + n * 16 + fr;
                int pc = (kh * 4 + fq) ^ (r & 7);
                bf_[n] = *(const short8*)(&Bs[cur][(r * 8 + pc) * 8]);
            }
            __builtin_amdgcn_s_setprio(1);
#pragma unroll
            for (int m = 0; m < 8; ++m)
#pragma unroll
                for (int n = 0; n < 4; ++n)
                    acc[m][n] = __builtin_amdgcn_mfma_f32_16x16x32_bf16(af[m], bf_[n], acc[m][n], 0, 0, 0);
            __builtin_amdgcn_s_setprio(0);
        }
        BARRIER_RAW();          // all reads of cur done before next STAGE overwrites
        cur ^= 1;
    }
#undef STAGE

#pragma unroll
    for (int m = 0; m < 8; ++m)
#pragma unroll
        for (int n = 0; n < 4; ++n) {
            size_t col = bn + wc + n * 16 + fr;
            float dcol = (EPI == 1) ? Dvec[col] : 0.0f;
#pragma unroll
            for (int r = 0; r < 4; ++r) {
                size_t row = bm + wr + m * 16 + fq * 4 + r;
                float v = acc[m][n][r];
                if (EPI == 1) {
                    v = fmaf(dcol, __bfloat162float(Ubf[row * 1024 + col]), v);
                    ((float*)CoutV)[row * 1024 + col] = fmaxf(v, 0.0f);
                } else {
                    ((__hip_bfloat16*)CoutV)[row * 1024 + col] = __float2bfloat16(v);
                }
            }
        }
}

// ======== scan pass 1: per-(b,chunk) totals over CLEN=32 steps ========
// thread t handles ADJACENT states 2t, 2t+1 (uint2 loads, 8B/lane); 512 blocks.
__global__ __launch_bounds__(256) void scan_totals(const unsigned* __restrict__ Bub,
                                                   const float* __restrict__ P,
                                                   float* __restrict__ T) {
    const int b = blockIdx.x >> 7;              // NCH=128
    const int c = blockIdx.x & 127;
    const int t = threadIdx.x;
    const int n0 = 2 * t, n1 = 2 * t + 1;
    const float l0r = P[n0 * 6 + 2], l0i = P[n0 * 6 + 3];
    const float l1r = P[n1 * 6 + 2], l1i = P[n1 * 6 + 3];
    const uint2* base = (const uint2*)(Bub + ((size_t)(b * SEQ + c * CLEN)) * 512);
    float x0r = 0.f, x0i = 0.f, x1r = 0.f, x1i = 0.f;
    for (int j = 0; j < CLEN; ++j) {
        uint2 p = base[(size_t)j * 256 + t];
        float v0x = bf2f((unsigned short)(p.x & 0xffff)), v0y = bf2f((unsigned short)(p.x >> 16));
        float v1x = bf2f((unsigned short)(p.y & 0xffff)), v1y = bf2f((unsigned short)(p.y >> 16));
        float nr = fmaf(l0r, x0r, fmaf(-l0i, x0i, v0x));
        float ni = fmaf(l0r, x0i, fmaf(l0i, x0r, v0y));
        x0r = nr; x0i = ni;
        nr = fmaf(l1r, x1r, fmaf(-l1i, x1i, v1x));
        ni = fmaf(l1r, x1i, fmaf(l1i, x1r, v1y));
        x1r = nr; x1i = ni;
    }
    float4* Tp = (float4*)(T + ((size_t)(b * NCH + c)) * 1024);
    Tp[t] = make_float4(x0r, x0i, x1r, x1i);    // states 2t, 2t+1
}

// ============ scan pass 2: exclusive carry across chunks (lambda^32 per hop) ====
__global__ __launch_bounds__(256) void scan_carry(const float* __restrict__ T,
                                                  const float* __restrict__ P,
                                                  float* __restrict__ Cry) {
    int idx = blockIdx.x * 256 + threadIdx.x;   // b*512 + n
    if (idx >= NB * NS) return;
    int b = idx >> 9, n = idx & 511;
    float wre = P[n * 6 + 0] * (float)CLEN, wim = P[n * 6 + 1] * (float)CLEN;
    float s, c;
    sincosf(wim, &s, &c);
    float e = expf(wre);
    float cr = e * c, ci = e * s;   // lambda^CLEN
    float xr = 0.f, xi = 0.f;
    const float2* Tp = (const float2*)T;
    float2* Cp = (float2*)Cry;
    for (int ch = 0; ch < NCH; ++ch) {
        size_t o = ((size_t)(b * NCH + ch)) * 512 + n;
        Cp[o] = make_float2(xr, xi);
        float2 tv = Tp[o];
        float nr = fmaf(cr, xr, fmaf(-ci, xi, tv.x));
        float ni = fmaf(cr, xi, fmaf(ci, xr, tv.y));
        xr = nr; xi = ni;
    }
}

// ==== scan pass 3: apply carry; write state REAL (f32) + full state (bf16) ====
__global__ __launch_bounds__(256) void scan_final(const unsigned* __restrict__ Bub,
                                                  const float* __restrict__ P,
                                                  const float* __restrict__ Cry,
                                                  float* __restrict__ Sre,
                                                  __hip_bfloat16* __restrict__ Sbf) {
    const int b = blockIdx.x >> 7;              // NCH=128
    const int c = blockIdx.x & 127;
    const int t = threadIdx.x;
    const int n0 = 2 * t, n1 = 2 * t + 1;
    const float l0r = P[n0 * 6 + 2], l0i = P[n0 * 6 + 3];
    const float l1r = P[n1 * 6 + 2], l1i = P[n1 * 6 + 3];
    const uint2* base = (const uint2*)(Bub + ((size_t)(b * SEQ + c * CLEN)) * 512);
    const float4* Cp = (const float4*)(Cry + ((size_t)(b * NCH + c)) * 1024);
    float4 c01 = Cp[t];
    float x0r = c01.x, x0i = c01.y, x1r = c01.z, x1i = c01.w;
    for (int j = 0; j < CLEN; ++j) {
        uint2 p = base[(size_t)j * 256 + t];
        float v0x = bf2f((unsigned short)(p.x & 0xffff)), v0y = bf2f((unsigned short)(p.x >> 16));
        float v1x = bf2f((unsigned short)(p.y & 0xffff)), v1y = bf2f((unsigned short)(p.y >> 16));
        float nr = fmaf(l0r, x0r, fmaf(-l0i, x0i, v0x));
        float ni = fmaf(l0r, x0i, fmaf(l0i, x0r, v0y));
        x0r = nr; x0i = ni;
        nr = fmaf(l1r, x1r, fmaf(-l1i, x1i, v1x));
        ni = fmaf(l1r, x1i, fmaf(l1i, x1r, v1y));
        x1r = nr; x1i = ni;
        size_t m = (size_t)b * SEQ + c * CLEN + j;
        // Output 1: real(state) f32, states 2t,2t+1 -> float2 store
        ((float2*)(Sre + m * 512))[t] = make_float2(x0r, x1r);
        // bf16 interleaved (re,im) for GEMM2: 4 bf16 = uint2 store
        union { __hip_bfloat16 h[2]; unsigned uu; } q0, q1;
        q0.h[0] = __float2bfloat16(x0r); q0.h[1] = __float2bfloat16(x0i);
        q1.h[0] = __float2bfloat16(x1r); q1.h[1] = __float2bfloat16(x1i);
        ((uint2*)(Sbf + m * 1024))[t] = make_uint2(q0.uu, q1.uu);
    }
}

// ==================== launch ====================
extern "C" void kernel_launch(void* const* d_in, const int* in_sizes, int n_in,
                              void* d_out, int out_size, void* d_ws, size_t ws_size,
                              hipStream_t stream) {
    const float* u    = (const float*)d_in[0];
    const float* Lre  = (const float*)d_in[1];
    const float* Lim  = (const float*)d_in[2];
    const float* Bin  = (const float*)d_in[3];
    const float* Cin  = (const float*)d_in[4];
    const float* Dv   = (const float*)d_in[5];
    const float* step = (const float*)d_in[6];

    char* ws = (char*)d_ws;
    __hip_bfloat16* Ubf = (__hip_bfloat16*)(ws + OFF_UBF);
    __hip_bfloat16* W1t = (__hip_bfloat16*)(ws + OFF_W1);
    __hip_bfloat16* W2t = (__hip_bfloat16*)(ws + OFF_W2);
    float*          P   = (float*)(ws + OFF_P);
    __hip_bfloat16* Bu  = (__hip_bfloat16*)(ws + OFF_BU);
    float*          T   = (float*)(ws + OFF_T);
    float*          Cry = (float*)(ws + OFF_CRY);
    __hip_bfloat16* Sbf = (__hip_bfloat16*)(ws + OFF_SBF);

    float* y_out = (float*)d_out;
    constexpr int Y_ELEMS = MROWS * HD;          // 16,777,216 floats (y)
    constexpr int S_ELEMS = MROWS * NS;          // 8,388,608 floats (real(state))
    float* state_out = (out_size >= Y_ELEMS + S_ELEMS) ? (y_out + Y_ELEMS)
                                                       : (float*)(ws + OFF_STF);

    prep_params<<<8, 64, 0, stream>>>(Lre, Lim, step, P);
    build_weights<<<4096, 256, 0, stream>>>(Bin, Cin, P, W1t, W2t);
    cast_to_bf16<<<(MROWS * HD / 8) / 256, 256, 0, stream>>>(u, Ubf, MROWS * HD / 8);

    dim3 gg(MROWS / 256, HD / 256);   // 64 x 4 = 256 blocks = 1/CU
    gemm_bf16_256<0><<<gg, 512, 0, stream>>>(Ubf, W1t, (void*)Bu, nullptr, nullptr);

    scan_totals<<<NB * NCH, 256, 0, stream>>>((const unsigned*)Bu, P, T);
    scan_carry<<<(NB * NS + 255) / 256, 256, 0, stream>>>(T, P, Cry);
    scan_final<<<NB * NCH, 256, 0, stream>>>((const unsigned*)Bu, P, Cry, state_out, Sbf);

    gemm_bf16_256<1><<<gg, 512, 0, stream>>>(Sbf, W2t, (void*)y_out, Dv, Ubf);
}

// Round 13
// 137.655 us; speedup vs baseline: 1.0588x; 1.0588x over previous
//
#include <hip/hip_runtime.h>
#include <hip/hip_bf16.h>

typedef __attribute__((ext_vector_type(8))) short short8;
typedef __attribute__((ext_vector_type(4))) float f32x4;

#define DEVI __device__ __forceinline__

constexpr int SEQ = 4096;
constexpr int HD = 1024;      // d_model
constexpr int NS = 512;       // ssm size
constexpr int NB = 4;         // batch
constexpr int MROWS = NB * SEQ;        // 16384
constexpr int NCH = 64;                // chunks along L
constexpr int CLEN = SEQ / NCH;        // 64

// ---- workspace byte offsets ----
constexpr size_t MB = 1024 * 1024;
constexpr size_t OFF_UBF = 0;                 // u bf16 (M x 1024) 32 MiB
constexpr size_t OFF_W1  = 32 * MB;           // W1t (1024 x 1024 bf16) 2 MiB
constexpr size_t OFF_W2  = 34 * MB;           // W2t 2 MiB
constexpr size_t OFF_P   = 36 * MB;           // per-n params (64 KiB reserved)
constexpr size_t OFF_BU  = 36 * MB + 65536;   // Bu bf16 (M x 1024) 32 MiB
constexpr size_t OFF_T   = OFF_BU + 32 * MB;  // chunk totals (f32) 1 MiB
constexpr size_t OFF_CRY = OFF_T + 1 * MB;    // carries (f32) 1 MiB
constexpr size_t OFF_SBF = OFF_CRY + 1 * MB;  // state bf16 32 MiB
constexpr size_t OFF_STF = OFF_SBF + 32 * MB; // state-real f32 fallback 32 MiB

DEVI float bf2f(unsigned short u) {
    union { unsigned u32; float f; } x; x.u32 = (unsigned)u << 16; return x.f;
}

// ============ prep: per-n lambda_bar and f = (lb-1)/Lambda ============
__global__ void prep_params(const float* __restrict__ Lre, const float* __restrict__ Lim,
                            const float* __restrict__ step, float* __restrict__ P) {
    int n = blockIdx.x * 64 + threadIdx.x;
    if (n >= NS) return;
    float dt  = expf(step[n]);
    float lre = fminf(Lre[n], -1e-4f);
    float lim = Lim[n];
    float wre = lre * dt, wim = lim * dt;
    float s, c;
    sincosf(wim, &s, &c);
    float e = expf(wre);
    float lbre = e * c, lbim = e * s;
    float em1 = expm1f(wre);
    float sh  = sinf(0.5f * wim);
    float nr  = em1 * c - 2.0f * sh * sh;   // e^wre*cos(wim) - 1
    float ni  = e * s;
    float d2  = lre * lre + lim * lim;
    float inv = 1.0f / d2;
    float fre = (nr * lre + ni * lim) * inv;
    float fim = (ni * lre - nr * lim) * inv;
    float* p = P + n * 6;
    p[0] = wre; p[1] = wim; p[2] = lbre; p[3] = lbim; p[4] = fre; p[5] = fim;
}

// ====== merged weight build: blocks [0,2048) -> W1t, [2048,4096) -> W2t ======
__global__ void build_weights(const float* __restrict__ Bin, const float* __restrict__ Cin,
                              const float* __restrict__ P,
                              __hip_bfloat16* __restrict__ W1t,
                              __hip_bfloat16* __restrict__ W2t) {
    int bid = blockIdx.x;
    if (bid < 2048) {
        int idx = bid * 256 + threadIdx.x;          // n*HD + k
        int n = idx >> 10, k = idx & 1023;
        float fre = P[n * 6 + 4], fim = P[n * 6 + 5];
        float bre = Bin[(size_t)idx * 2 + 0], bim = Bin[(size_t)idx * 2 + 1];
        W1t[(size_t)(2 * n) * HD + k]     = __float2bfloat16(fre * bre - fim * bim);
        W1t[(size_t)(2 * n + 1) * HD + k] = __float2bfloat16(fre * bim + fim * bre);
    } else {
        int idx = (bid - 2048) * 256 + threadIdx.x; // h*NS + n
        int h = idx >> 9, n = idx & 511;
        float cre = Cin[(size_t)idx * 2 + 0], cim = Cin[(size_t)idx * 2 + 1];
        W2t[(size_t)h * HD + 2 * n]     = __float2bfloat16(cre);
        W2t[(size_t)h * HD + 2 * n + 1] = __float2bfloat16(-cim);
    }
}

// ============ f32 -> bf16 cast, 8/thread ============
__global__ void cast_to_bf16(const float* __restrict__ x, __hip_bfloat16* __restrict__ y, int n8) {
    int i = blockIdx.x * 256 + threadIdx.x;
    if (i >= n8) return;
    const float4* xv = (const float4*)x;
    float4 a = xv[2 * (size_t)i], b = xv[2 * (size_t)i + 1];
    union { __hip_bfloat16 h[8]; short8 v; } u8;
    u8.h[0] = __float2bfloat16(a.x); u8.h[1] = __float2bfloat16(a.y);
    u8.h[2] = __float2bfloat16(a.z); u8.h[3] = __float2bfloat16(a.w);
    u8.h[4] = __float2bfloat16(b.x); u8.h[5] = __float2bfloat16(b.y);
    u8.h[6] = __float2bfloat16(b.z); u8.h[7] = __float2bfloat16(b.w);
    *((short8*)(y + (size_t)i * 8)) = u8.v;
}

// ========== GEMM 256x256, BK=64, 8 waves, dbuf, counted vmcnt + XOR swizzle ======
// EXACT round-11 champion kernel (138.1us): no setprio (m190 confirmed on our
// own structure in round 12).
DEVI void gload16(const __hip_bfloat16* g, __hip_bfloat16* l) {
    __builtin_amdgcn_global_load_lds(
        (const __attribute__((address_space(1))) unsigned int*)g,
        (__attribute__((address_space(3))) unsigned int*)l,
        16, 0, 0);
}

#define BARRIER_RAW() { asm volatile("" ::: "memory"); __builtin_amdgcn_s_barrier(); asm volatile("" ::: "memory"); }

template <int EPI>
__global__ __launch_bounds__(512, 2) void gemm_bf16_256(
    const __hip_bfloat16* __restrict__ A,   // M x 1024 row-major
    const __hip_bfloat16* __restrict__ Bt,  // 1024 x 1024 row-major (N x K)
    void* __restrict__ CoutV,               // M x 1024 (bf16 if EPI==0, f32 if EPI==1)
    const float* __restrict__ Dvec,         // [1024] (EPI==1)
    const __hip_bfloat16* __restrict__ Ubf) // M x 1024 bf16 (EPI==1)
{
    // 2 dbuf x (A,B) x 256 rows x 64 cols bf16 = 128 KiB
    __shared__ __hip_bfloat16 As[2][256 * 64];
    __shared__ __hip_bfloat16 Bs[2][256 * 64];
    const int tid  = threadIdx.x;
    const int lane = tid & 63;
    const int wid  = tid >> 6;                  // 0..7
    const size_t bm = (size_t)blockIdx.x * 256;
    const size_t bn = (size_t)blockIdx.y * 256;
    const int wr = (wid >> 2) * 128;            // wave row origin: 0 / 128
    const int wc = (wid & 3) * 64;              // wave col origin: 0..192
    const int fr = lane & 15;
    const int fq = lane >> 4;

    f32x4 acc[8][4];
#pragma unroll
    for (int i = 0; i < 8; ++i)
#pragma unroll
        for (int j = 0; j < 4; ++j) acc[i][j] = (f32x4){0.f, 0.f, 0.f, 0.f};

    const int srow = tid >> 3;          // 0..63 per round (row within 64-row group)
    const int schk = tid & 7;           // logical 16B chunk 0..7

    // Pre-swizzled global column: LDS chunk (tid&7) receives global chunk
    // ((tid&7) ^ (row&7)). Involution: read of logical chunk c at row r uses
    // physical chunk c^(r&7)  ->  global col (c^(r&7))^(r&7) = c.
#define STAGE(buf, kt)                                                          \
    {                                                                           \
        _Pragma("unroll")                                                       \
        for (int q = 0; q < 4; ++q) {                                           \
            int row = q * 64 + srow;                                            \
            int gcol = (schk ^ (row & 7)) * 8;                                  \
            gload16(A  + (bm + row) * 1024 + (kt) + gcol, &As[buf][(row * 8 + schk) * 8]); \
            gload16(Bt + (bn + row) * 1024 + (kt) + gcol, &Bs[buf][(row * 8 + schk) * 8]); \
        }                                                                       \
    }

    // prologue: tile 0 staged and fully drained
    STAGE(0, 0);
    __syncthreads();

    int cur = 0;
    for (int t = 0; t < 16; ++t) {
        if (t < 15) {
            STAGE(cur ^ 1, (t + 1) * 64);   // 8 loads for tile t+1 — stay in flight
            asm volatile("s_waitcnt vmcnt(8)" ::: "memory");   // tile t's 8 retired
        } else {
            asm volatile("s_waitcnt vmcnt(0)" ::: "memory");   // final tile: drain
        }
        __builtin_amdgcn_sched_barrier(0);
        BARRIER_RAW();          // cross-wave: everyone's tile-t loads retired

#pragma unroll
        for (int kh = 0; kh < 2; ++kh) {
            short8 af[8], bf_[4];
#pragma unroll
            for (int m = 0; m < 8; ++m) {
                int r = wr + m * 16 + fr;
                int pc = (kh * 4 + fq) ^ (r & 7);           // physical 16B chunk
                af[m] = *(const short8*)(&As[cur][(r * 8 + pc) * 8]);
            }
#pragma unroll
            for (int n = 0; n < 4; ++n) {
                int r = wc + n * 16 + fr;
                int pc = (kh * 4 + fq) ^ (r & 7);
                bf_[n] = *(const short8*)(&Bs[cur][(r * 8 + pc) * 8]);
            }
#pragma unroll
            for (int m = 0; m < 8; ++m)
#pragma unroll
                for (int n = 0; n < 4; ++n)
                    acc[m][n] = __builtin_amdgcn_mfma_f32_16x16x32_bf16(af[m], bf_[n], acc[m][n], 0, 0, 0);
        }
        BARRIER_RAW();          // all reads of cur done before next STAGE overwrites
        cur ^= 1;
    }
#undef STAGE

#pragma unroll
    for (int m = 0; m < 8; ++m)
#pragma unroll
        for (int n = 0; n < 4; ++n) {
            size_t col = bn + wc + n * 16 + fr;
            float dcol = (EPI == 1) ? Dvec[col] : 0.0f;
#pragma unroll
            for (int r = 0; r < 4; ++r) {
                size_t row = bm + wr + m * 16 + fq * 4 + r;
                float v = acc[m][n][r];
                if (EPI == 1) {
                    v = fmaf(dcol, __bfloat162float(Ubf[row * 1024 + col]), v);
                    ((float*)CoutV)[row * 1024 + col] = fmaxf(v, 0.0f);
                } else {
                    ((__hip_bfloat16*)CoutV)[row * 1024 + col] = __float2bfloat16(v);
                }
            }
        }
}

// ======== scan pass 1: per-(b,chunk) totals over CLEN=64 steps ========
// thread t handles ADJACENT states 2t, 2t+1 (uint2 loads, 8B/lane).
__global__ __launch_bounds__(256) void scan_totals(const unsigned* __restrict__ Bub,
                                                   const float* __restrict__ P,
                                                   float* __restrict__ T) {
    const int b = blockIdx.x >> 6;              // NCH=64
    const int c = blockIdx.x & 63;
    const int t = threadIdx.x;
    const int n0 = 2 * t, n1 = 2 * t + 1;
    const float l0r = P[n0 * 6 + 2], l0i = P[n0 * 6 + 3];
    const float l1r = P[n1 * 6 + 2], l1i = P[n1 * 6 + 3];
    const uint2* base = (const uint2*)(Bub + ((size_t)(b * SEQ + c * CLEN)) * 512);
    float x0r = 0.f, x0i = 0.f, x1r = 0.f, x1i = 0.f;
    for (int j = 0; j < CLEN; ++j) {
        uint2 p = base[(size_t)j * 256 + t];
        float v0x = bf2f((unsigned short)(p.x & 0xffff)), v0y = bf2f((unsigned short)(p.x >> 16));
        float v1x = bf2f((unsigned short)(p.y & 0xffff)), v1y = bf2f((unsigned short)(p.y >> 16));
        float nr = fmaf(l0r, x0r, fmaf(-l0i, x0i, v0x));
        float ni = fmaf(l0r, x0i, fmaf(l0i, x0r, v0y));
        x0r = nr; x0i = ni;
        nr = fmaf(l1r, x1r, fmaf(-l1i, x1i, v1x));
        ni = fmaf(l1r, x1i, fmaf(l1i, x1r, v1y));
        x1r = nr; x1i = ni;
    }
    float4* Tp = (float4*)(T + ((size_t)(b * NCH + c)) * 1024);
    Tp[t] = make_float4(x0r, x0i, x1r, x1i);    // states 2t, 2t+1 (same layout as float2@n)
}

// ============ scan pass 2: exclusive carry across chunks (lambda^64 per hop) ====
__global__ __launch_bounds__(256) void scan_carry(const float* __restrict__ T,
                                                  const float* __restrict__ P,
                                                  float* __restrict__ Cry) {
    int idx = blockIdx.x * 256 + threadIdx.x;   // b*512 + n
    if (idx >= NB * NS) return;
    int b = idx >> 9, n = idx & 511;
    float wre = P[n * 6 + 0] * (float)CLEN, wim = P[n * 6 + 1] * (float)CLEN;
    float s, c;
    sincosf(wim, &s, &c);
    float e = expf(wre);
    float cr = e * c, ci = e * s;   // lambda^CLEN
    float xr = 0.f, xi = 0.f;
    const float2* Tp = (const float2*)T;
    float2* Cp = (float2*)Cry;
    for (int ch = 0; ch < NCH; ++ch) {
        size_t o = ((size_t)(b * NCH + ch)) * 512 + n;
        Cp[o] = make_float2(xr, xi);
        float2 tv = Tp[o];
        float nr = fmaf(cr, xr, fmaf(-ci, xi, tv.x));
        float ni = fmaf(cr, xi, fmaf(ci, xr, tv.y));
        xr = nr; xi = ni;
    }
}

// ==== scan pass 3: apply carry; write state REAL (f32) + full state (bf16) ====
__global__ __launch_bounds__(256) void scan_final(const unsigned* __restrict__ Bub,
                                                  const float* __restrict__ P,
                                                  const float* __restrict__ Cry,
                                                  float* __restrict__ Sre,
                                                  __hip_bfloat16* __restrict__ Sbf) {
    const int b = blockIdx.x >> 6;              // NCH=64
    const int c = blockIdx.x & 63;
    const int t = threadIdx.x;
    const int n0 = 2 * t, n1 = 2 * t + 1;
    const float l0r = P[n0 * 6 + 2], l0i = P[n0 * 6 + 3];
    const float l1r = P[n1 * 6 + 2], l1i = P[n1 * 6 + 3];
    const uint2* base = (const uint2*)(Bub + ((size_t)(b * SEQ + c * CLEN)) * 512);
    const float4* Cp = (const float4*)(Cry + ((size_t)(b * NCH + c)) * 1024);
    float4 c01 = Cp[t];
    float x0r = c01.x, x0i = c01.y, x1r = c01.z, x1i = c01.w;
    for (int j = 0; j < CLEN; ++j) {
        uint2 p = base[(size_t)j * 256 + t];
        float v0x = bf2f((unsigned short)(p.x & 0xffff)), v0y = bf2f((unsigned short)(p.x >> 16));
        float v1x = bf2f((unsigned short)(p.y & 0xffff)), v1y = bf2f((unsigned short)(p.y >> 16));
        float nr = fmaf(l0r, x0r, fmaf(-l0i, x0i, v0x));
        float ni = fmaf(l0r, x0i, fmaf(l0i, x0r, v0y));
        x0r = nr; x0i = ni;
        nr = fmaf(l1r, x1r, fmaf(-l1i, x1i, v1x));
        ni = fmaf(l1r, x1i, fmaf(l1i, x1r, v1y));
        x1r = nr; x1i = ni;
        size_t m = (size_t)b * SEQ + c * CLEN + j;
        // Output 1: real(state) f32, states 2t,2t+1 -> float2 store
        ((float2*)(Sre + m * 512))[t] = make_float2(x0r, x1r);
        // bf16 interleaved (re,im) for GEMM2: 4 bf16 = uint2 store
        union { __hip_bfloat16 h[2]; unsigned uu; } q0, q1;
        q0.h[0] = __float2bfloat16(x0r); q0.h[1] = __float2bfloat16(x0i);
        q1.h[0] = __float2bfloat16(x1r); q1.h[1] = __float2bfloat16(x1i);
        ((uint2*)(Sbf + m * 1024))[t] = make_uint2(q0.uu, q1.uu);
    }
}

// ==================== launch ====================
extern "C" void kernel_launch(void* const* d_in, const int* in_sizes, int n_in,
                              void* d_out, int out_size, void* d_ws, size_t ws_size,
                              hipStream_t stream) {
    const float* u    = (const float*)d_in[0];
    const float* Lre  = (const float*)d_in[1];
    const float* Lim  = (const float*)d_in[2];
    const float* Bin  = (const float*)d_in[3];
    const float* Cin  = (const float*)d_in[4];
    const float* Dv   = (const float*)d_in[5];
    const float* step = (const float*)d_in[6];

    char* ws = (char*)d_ws;
    __hip_bfloat16* Ubf = (__hip_bfloat16*)(ws + OFF_UBF);
    __hip_bfloat16* W1t = (__hip_bfloat16*)(ws + OFF_W1);
    __hip_bfloat16* W2t = (__hip_bfloat16*)(ws + OFF_W2);
    float*          P   = (float*)(ws + OFF_P);
    __hip_bfloat16* Bu  = (__hip_bfloat16*)(ws + OFF_BU);
    float*          T   = (float*)(ws + OFF_T);
    float*          Cry = (float*)(ws + OFF_CRY);
    __hip_bfloat16* Sbf = (__hip_bfloat16*)(ws + OFF_SBF);

    float* y_out = (float*)d_out;
    constexpr int Y_ELEMS = MROWS * HD;          // 16,777,216 floats (y)
    constexpr int S_ELEMS = MROWS * NS;          // 8,388,608 floats (real(state))
    float* state_out = (out_size >= Y_ELEMS + S_ELEMS) ? (y_out + Y_ELEMS)
                                                       : (float*)(ws + OFF_STF);

    prep_params<<<8, 64, 0, stream>>>(Lre, Lim, step, P);
    build_weights<<<4096, 256, 0, stream>>>(Bin, Cin, P, W1t, W2t);
    cast_to_bf16<<<(MROWS * HD / 8) / 256, 256, 0, stream>>>(u, Ubf, MROWS * HD / 8);

    dim3 gg(MROWS / 256, HD / 256);   // 64 x 4 = 256 blocks = 1/CU
    gemm_bf16_256<0><<<gg, 512, 0, stream>>>(Ubf, W1t, (void*)Bu, nullptr, nullptr);

    scan_totals<<<NB * NCH, 256, 0, stream>>>((const unsigned*)Bu, P, T);
    scan_carry<<<(NB * NS + 255) / 256, 256, 0, stream>>>(T, P, Cry);
    scan_final<<<NB * NCH, 256, 0, stream>>>((const unsigned*)Bu, P, Cry, state_out, Sbf);

    gemm_bf16_256<1><<<gg, 512, 0, stream>>>(Sbf, W2t, (void*)y_out, Dv, Ubf);
}

// Round 14
// 132.168 us; speedup vs baseline: 1.1027x; 1.0415x over previous
//
#include <hip/hip_runtime.h>
#include <hip/hip_bf16.h>

typedef __attribute__((ext_vector_type(8))) short short8;
typedef __attribute__((ext_vector_type(4))) float f32x4;

#define DEVI __device__ __forceinline__

constexpr int SEQ = 4096;
constexpr int HD = 1024;      // d_model
constexpr int NS = 512;       // ssm size
constexpr int NB = 4;         // batch
constexpr int MROWS = NB * SEQ;        // 16384
constexpr int NCH = 64;                // chunks along L
constexpr int CLEN = SEQ / NCH;        // 64

// ---- workspace byte offsets ----
constexpr size_t MB = 1024 * 1024;
constexpr size_t OFF_UBF = 0;                 // u bf16 (M x 1024) 32 MiB
constexpr size_t OFF_W1  = 32 * MB;           // W1t (1024 x 1024 bf16) 2 MiB
constexpr size_t OFF_W2  = 34 * MB;           // W2t 2 MiB
constexpr size_t OFF_BU  = 36 * MB + 65536;   // Bu bf16 (M x 1024) 32 MiB
constexpr size_t OFF_T   = OFF_BU + 32 * MB;  // chunk totals (f32) 1 MiB
constexpr size_t OFF_CRY = OFF_T + 1 * MB;    // carries (f32) 1 MiB
constexpr size_t OFF_SBF = OFF_CRY + 1 * MB;  // state bf16 32 MiB
constexpr size_t OFF_STF = OFF_SBF + 32 * MB; // state-real f32 fallback 32 MiB

DEVI float bf2f(unsigned short u) {
    union { unsigned u32; float f; } x; x.u32 = (unsigned)u << 16; return x.f;
}

// inline per-n discretization: lambda_bar = exp(w), w = lambda*dt
DEVI void lam_bar(const float* Lre, const float* Lim, const float* step, int n,
                  float& lbr, float& lbi) {
    float dt  = expf(step[n]);
    float lre = fminf(Lre[n], -1e-4f);
    float wre = lre * dt, wim = Lim[n] * dt;
    float s, c;
    sincosf(wim, &s, &c);
    float e = expf(wre);
    lbr = e * c; lbi = e * s;
}

// ====== merged pre-pass: [0,2048) W1t, [2048,4096) W2t, [4096,12288) cast u ======
__global__ void build_and_cast(const float* __restrict__ Bin, const float* __restrict__ Cin,
                               const float* __restrict__ Lre, const float* __restrict__ Lim,
                               const float* __restrict__ step, const float* __restrict__ u,
                               __hip_bfloat16* __restrict__ W1t,
                               __hip_bfloat16* __restrict__ W2t,
                               __hip_bfloat16* __restrict__ Ubf) {
    int bid = blockIdx.x;
    if (bid < 2048) {
        int idx = bid * 256 + threadIdx.x;          // n*HD + k
        int n = idx >> 10, k = idx & 1023;
        // f = (lambda_bar - 1)/lambda, cancellation-safe (wave-uniform n)
        float dt  = expf(step[n]);
        float lre = fminf(Lre[n], -1e-4f);
        float lim = Lim[n];
        float wre = lre * dt, wim = lim * dt;
        float s, c;
        sincosf(wim, &s, &c);
        float e   = expf(wre);
        float em1 = expm1f(wre);
        float sh  = sinf(0.5f * wim);
        float nrm = em1 * c - 2.0f * sh * sh;       // e^wre*cos(wim) - 1
        float nim = e * s;
        float inv = 1.0f / (lre * lre + lim * lim);
        float fre = (nrm * lre + nim * lim) * inv;
        float fim = (nim * lre - nrm * lim) * inv;
        float bre = Bin[(size_t)idx * 2 + 0], bim = Bin[(size_t)idx * 2 + 1];
        W1t[(size_t)(2 * n) * HD + k]     = __float2bfloat16(fre * bre - fim * bim);
        W1t[(size_t)(2 * n + 1) * HD + k] = __float2bfloat16(fre * bim + fim * bre);
    } else if (bid < 4096) {
        int idx = (bid - 2048) * 256 + threadIdx.x; // h*NS + n
        int h = idx >> 9, n = idx & 511;
        float cre = Cin[(size_t)idx * 2 + 0], cim = Cin[(size_t)idx * 2 + 1];
        W2t[(size_t)h * HD + 2 * n]     = __float2bfloat16(cre);
        W2t[(size_t)h * HD + 2 * n + 1] = __float2bfloat16(-cim);
    } else {
        int i = (bid - 4096) * 256 + threadIdx.x;   // 8 f32 -> 8 bf16
        const float4* xv = (const float4*)u;
        float4 a = xv[2 * (size_t)i], b = xv[2 * (size_t)i + 1];
        union { __hip_bfloat16 h[8]; short8 v; } u8;
        u8.h[0] = __float2bfloat16(a.x); u8.h[1] = __float2bfloat16(a.y);
        u8.h[2] = __float2bfloat16(a.z); u8.h[3] = __float2bfloat16(a.w);
        u8.h[4] = __float2bfloat16(b.x); u8.h[5] = __float2bfloat16(b.y);
        u8.h[6] = __float2bfloat16(b.z); u8.h[7] = __float2bfloat16(b.w);
        *((short8*)(Ubf + (size_t)i * 8)) = u8.v;
    }
}

// ========== GEMM 256x256, BK=64, 8 waves, dbuf, counted vmcnt + XOR swizzle ======
// EXACT round-11/13 champion kernel.
DEVI void gload16(const __hip_bfloat16* g, __hip_bfloat16* l) {
    __builtin_amdgcn_global_load_lds(
        (const __attribute__((address_space(1))) unsigned int*)g,
        (__attribute__((address_space(3))) unsigned int*)l,
        16, 0, 0);
}

#define BARRIER_RAW() { asm volatile("" ::: "memory"); __builtin_amdgcn_s_barrier(); asm volatile("" ::: "memory"); }

template <int EPI>
__global__ __launch_bounds__(512, 2) void gemm_bf16_256(
    const __hip_bfloat16* __restrict__ A,   // M x 1024 row-major
    const __hip_bfloat16* __restrict__ Bt,  // 1024 x 1024 row-major (N x K)
    void* __restrict__ CoutV,               // M x 1024 (bf16 if EPI==0, f32 if EPI==1)
    const float* __restrict__ Dvec,         // [1024] (EPI==1)
    const __hip_bfloat16* __restrict__ Ubf) // M x 1024 bf16 (EPI==1)
{
    // 2 dbuf x (A,B) x 256 rows x 64 cols bf16 = 128 KiB
    __shared__ __hip_bfloat16 As[2][256 * 64];
    __shared__ __hip_bfloat16 Bs[2][256 * 64];
    const int tid  = threadIdx.x;
    const int lane = tid & 63;
    const int wid  = tid >> 6;                  // 0..7
    const size_t bm = (size_t)blockIdx.x * 256;
    const size_t bn = (size_t)blockIdx.y * 256;
    const int wr = (wid >> 2) * 128;            // wave row origin: 0 / 128
    const int wc = (wid & 3) * 64;              // wave col origin: 0..192
    const int fr = lane & 15;
    const int fq = lane >> 4;

    f32x4 acc[8][4];
#pragma unroll
    for (int i = 0; i < 8; ++i)
#pragma unroll
        for (int j = 0; j < 4; ++j) acc[i][j] = (f32x4){0.f, 0.f, 0.f, 0.f};

    const int srow = tid >> 3;          // 0..63 per round (row within 64-row group)
    const int schk = tid & 7;           // logical 16B chunk 0..7

    // Pre-swizzled global column: LDS chunk (tid&7) receives global chunk
    // ((tid&7) ^ (row&7)). Involution: read of logical chunk c at row r uses
    // physical chunk c^(r&7)  ->  global col (c^(r&7))^(r&7) = c.
#define STAGE(buf, kt)                                                          \
    {                                                                           \
        _Pragma("unroll")                                                       \
        for (int q = 0; q < 4; ++q) {                                           \
            int row = q * 64 + srow;                                            \
            int gcol = (schk ^ (row & 7)) * 8;                                  \
            gload16(A  + (bm + row) * 1024 + (kt) + gcol, &As[buf][(row * 8 + schk) * 8]); \
            gload16(Bt + (bn + row) * 1024 + (kt) + gcol, &Bs[buf][(row * 8 + schk) * 8]); \
        }                                                                       \
    }

    // prologue: tile 0 staged and fully drained
    STAGE(0, 0);
    __syncthreads();

    int cur = 0;
    for (int t = 0; t < 16; ++t) {
        if (t < 15) {
            STAGE(cur ^ 1, (t + 1) * 64);   // 8 loads for tile t+1 — stay in flight
            asm volatile("s_waitcnt vmcnt(8)" ::: "memory");   // tile t's 8 retired
        } else {
            asm volatile("s_waitcnt vmcnt(0)" ::: "memory");   // final tile: drain
        }
        __builtin_amdgcn_sched_barrier(0);
        BARRIER_RAW();          // cross-wave: everyone's tile-t loads retired

#pragma unroll
        for (int kh = 0; kh < 2; ++kh) {
            short8 af[8], bf_[4];
#pragma unroll
            for (int m = 0; m < 8; ++m) {
                int r = wr + m * 16 + fr;
                int pc = (kh * 4 + fq) ^ (r & 7);           // physical 16B chunk
                af[m] = *(const short8*)(&As[cur][(r * 8 + pc) * 8]);
            }
#pragma unroll
            for (int n = 0; n < 4; ++n) {
                int r = wc + n * 16 + fr;
                int pc = (kh * 4 + fq) ^ (r & 7);
                bf_[n] = *(const short8*)(&Bs[cur][(r * 8 + pc) * 8]);
            }
#pragma unroll
            for (int m = 0; m < 8; ++m)
#pragma unroll
                for (int n = 0; n < 4; ++n)
                    acc[m][n] = __builtin_amdgcn_mfma_f32_16x16x32_bf16(af[m], bf_[n], acc[m][n], 0, 0, 0);
        }
        BARRIER_RAW();          // all reads of cur done before next STAGE overwrites
        cur ^= 1;
    }
#undef STAGE

#pragma unroll
    for (int m = 0; m < 8; ++m)
#pragma unroll
        for (int n = 0; n < 4; ++n) {
            size_t col = bn + wc + n * 16 + fr;
            float dcol = (EPI == 1) ? Dvec[col] : 0.0f;
#pragma unroll
            for (int r = 0; r < 4; ++r) {
                size_t row = bm + wr + m * 16 + fq * 4 + r;
                float v = acc[m][n][r];
                if (EPI == 1) {
                    v = fmaf(dcol, __bfloat162float(Ubf[row * 1024 + col]), v);
                    ((float*)CoutV)[row * 1024 + col] = fmaxf(v, 0.0f);
                } else {
                    ((__hip_bfloat16*)CoutV)[row * 1024 + col] = __float2bfloat16(v);
                }
            }
        }
}

// ======== scan pass 1: per-(b,chunk) totals over CLEN=64 steps ========
// thread t handles ADJACENT states 2t, 2t+1 (uint2 loads); lambda_bar inline.
__global__ __launch_bounds__(256) void scan_totals(const unsigned* __restrict__ Bub,
                                                   const float* __restrict__ Lre,
                                                   const float* __restrict__ Lim,
                                                   const float* __restrict__ step,
                                                   float* __restrict__ T) {
    const int b = blockIdx.x >> 6;              // NCH=64
    const int c = blockIdx.x & 63;
    const int t = threadIdx.x;
    float l0r, l0i, l1r, l1i;
    lam_bar(Lre, Lim, step, 2 * t,     l0r, l0i);
    lam_bar(Lre, Lim, step, 2 * t + 1, l1r, l1i);
    const uint2* base = (const uint2*)(Bub + ((size_t)(b * SEQ + c * CLEN)) * 512);
    float x0r = 0.f, x0i = 0.f, x1r = 0.f, x1i = 0.f;
    for (int j = 0; j < CLEN; ++j) {
        uint2 p = base[(size_t)j * 256 + t];
        float v0x = bf2f((unsigned short)(p.x & 0xffff)), v0y = bf2f((unsigned short)(p.x >> 16));
        float v1x = bf2f((unsigned short)(p.y & 0xffff)), v1y = bf2f((unsigned short)(p.y >> 16));
        float nr = fmaf(l0r, x0r, fmaf(-l0i, x0i, v0x));
        float ni = fmaf(l0r, x0i, fmaf(l0i, x0r, v0y));
        x0r = nr; x0i = ni;
        nr = fmaf(l1r, x1r, fmaf(-l1i, x1i, v1x));
        ni = fmaf(l1r, x1i, fmaf(l1i, x1r, v1y));
        x1r = nr; x1i = ni;
    }
    float4* Tp = (float4*)(T + ((size_t)(b * NCH + c)) * 1024);
    Tp[t] = make_float4(x0r, x0i, x1r, x1i);    // states 2t, 2t+1
}

// ============ scan pass 2: exclusive carry across chunks (lambda^64 per hop) ====
__global__ __launch_bounds__(256) void scan_carry(const float* __restrict__ T,
                                                  const float* __restrict__ Lre,
                                                  const float* __restrict__ Lim,
                                                  const float* __restrict__ step,
                                                  float* __restrict__ Cry) {
    int idx = blockIdx.x * 256 + threadIdx.x;   // b*512 + n
    if (idx >= NB * NS) return;
    int b = idx >> 9, n = idx & 511;
    float dt  = expf(step[n]);
    float lre = fminf(Lre[n], -1e-4f);
    float wre = lre * dt * (float)CLEN, wim = Lim[n] * dt * (float)CLEN;
    float s, c;
    sincosf(wim, &s, &c);
    float e = expf(wre);
    float cr = e * c, ci = e * s;   // lambda^CLEN
    float xr = 0.f, xi = 0.f;
    const float2* Tp = (const float2*)T;
    float2* Cp = (float2*)Cry;
    for (int ch = 0; ch < NCH; ++ch) {
        size_t o = ((size_t)(b * NCH + ch)) * 512 + n;
        Cp[o] = make_float2(xr, xi);
        float2 tv = Tp[o];
        float nr = fmaf(cr, xr, fmaf(-ci, xi, tv.x));
        float ni = fmaf(cr, xi, fmaf(ci, xr, tv.y));
        xr = nr; xi = ni;
    }
}

// ==== scan pass 3: apply carry; write state REAL (f32) + full state (bf16) ====
__global__ __launch_bounds__(256) void scan_final(const unsigned* __restrict__ Bub,
                                                  const float* __restrict__ Lre,
                                                  const float* __restrict__ Lim,
                                                  const float* __restrict__ step,
                                                  const float* __restrict__ Cry,
                                                  float* __restrict__ Sre,
                                                  __hip_bfloat16* __restrict__ Sbf) {
    const int b = blockIdx.x >> 6;              // NCH=64
    const int c = blockIdx.x & 63;
    const int t = threadIdx.x;
    float l0r, l0i, l1r, l1i;
    lam_bar(Lre, Lim, step, 2 * t,     l0r, l0i);
    lam_bar(Lre, Lim, step, 2 * t + 1, l1r, l1i);
    const uint2* base = (const uint2*)(Bub + ((size_t)(b * SEQ + c * CLEN)) * 512);
    const float4* Cp = (const float4*)(Cry + ((size_t)(b * NCH + c)) * 1024);
    float4 c01 = Cp[t];
    float x0r = c01.x, x0i = c01.y, x1r = c01.z, x1i = c01.w;
    for (int j = 0; j < CLEN; ++j) {
        uint2 p = base[(size_t)j * 256 + t];
        float v0x = bf2f((unsigned short)(p.x & 0xffff)), v0y = bf2f((unsigned short)(p.x >> 16));
        float v1x = bf2f((unsigned short)(p.y & 0xffff)), v1y = bf2f((unsigned short)(p.y >> 16));
        float nr = fmaf(l0r, x0r, fmaf(-l0i, x0i, v0x));
        float ni = fmaf(l0r, x0i, fmaf(l0i, x0r, v0y));
        x0r = nr; x0i = ni;
        nr = fmaf(l1r, x1r, fmaf(-l1i, x1i, v1x));
        ni = fmaf(l1r, x1i, fmaf(l1i, x1r, v1y));
        x1r = nr; x1i = ni;
        size_t m = (size_t)b * SEQ + c * CLEN + j;
        ((float2*)(Sre + m * 512))[t] = make_float2(x0r, x1r);
        union { __hip_bfloat16 h[2]; unsigned uu; } q0, q1;
        q0.h[0] = __float2bfloat16(x0r); q0.h[1] = __float2bfloat16(x0i);
        q1.h[0] = __float2bfloat16(x1r); q1.h[1] = __float2bfloat16(x1i);
        ((uint2*)(Sbf + m * 1024))[t] = make_uint2(q0.uu, q1.uu);
    }
}

// ==================== launch ====================
extern "C" void kernel_launch(void* const* d_in, const int* in_sizes, int n_in,
                              void* d_out, int out_size, void* d_ws, size_t ws_size,
                              hipStream_t stream) {
    const float* u    = (const float*)d_in[0];
    const float* Lre  = (const float*)d_in[1];
    const float* Lim  = (const float*)d_in[2];
    const float* Bin  = (const float*)d_in[3];
    const float* Cin  = (const float*)d_in[4];
    const float* Dv   = (const float*)d_in[5];
    const float* step = (const float*)d_in[6];

    char* ws = (char*)d_ws;
    __hip_bfloat16* Ubf = (__hip_bfloat16*)(ws + OFF_UBF);
    __hip_bfloat16* W1t = (__hip_bfloat16*)(ws + OFF_W1);
    __hip_bfloat16* W2t = (__hip_bfloat16*)(ws + OFF_W2);
    __hip_bfloat16* Bu  = (__hip_bfloat16*)(ws + OFF_BU);
    float*          T   = (float*)(ws + OFF_T);
    float*          Cry = (float*)(ws + OFF_CRY);
    __hip_bfloat16* Sbf = (__hip_bfloat16*)(ws + OFF_SBF);

    float* y_out = (float*)d_out;
    constexpr int Y_ELEMS = MROWS * HD;          // 16,777,216 floats (y)
    constexpr int S_ELEMS = MROWS * NS;          // 8,388,608 floats (real(state))
    float* state_out = (out_size >= Y_ELEMS + S_ELEMS) ? (y_out + Y_ELEMS)
                                                       : (float*)(ws + OFF_STF);

    build_and_cast<<<12288, 256, 0, stream>>>(Bin, Cin, Lre, Lim, step, u, W1t, W2t, Ubf);

    dim3 gg(MROWS / 256, HD / 256);   // 64 x 4 = 256 blocks = 1/CU
    gemm_bf16_256<0><<<gg, 512, 0, stream>>>(Ubf, W1t, (void*)Bu, nullptr, nullptr);

    scan_totals<<<NB * NCH, 256, 0, stream>>>((const unsigned*)Bu, Lre, Lim, step, T);
    scan_carry<<<(NB * NS + 255) / 256, 256, 0, stream>>>(T, Lre, Lim, step, Cry);
    scan_final<<<NB * NCH, 256, 0, stream>>>((const unsigned*)Bu, Lre, Lim, step, Cry, state_out, Sbf);

    gemm_bf16_256<1><<<gg, 512, 0, stream>>>(Sbf, W2t, (void*)y_out, Dv, Ubf);
}